// Round 12
// baseline (385.539 us; speedup 1.0000x reference)
//
#include <hip/hip_runtime.h>

#define B_ 32
#define D_ 128
#define LC 2048
#define LQ 512
#define CCH 16   // col-partials count == LC/128 (one per k_S c-tile)
#define RCH 4    // row-partials count == LQ/128 (one per k_S q-tile)

#define NEGINF (-3.0e38f)

typedef __attribute__((ext_vector_type(8))) short bf16x8;
typedef __attribute__((ext_vector_type(4))) float f32x4;
typedef __attribute__((ext_vector_type(8))) unsigned short us8;
typedef __attribute__((ext_vector_type(8))) _Float16 f16x8;

__device__ __forceinline__ unsigned short bf16rne(float x) {
    unsigned int u = __float_as_uint(x);
    u = (u + 0x7FFFu + ((u >> 16) & 1u)) >> 16;
    return (unsigned short)u;
}

__device__ __forceinline__ void gll16(const void* g, void* l) {
    __builtin_amdgcn_global_load_lds((const __attribute__((address_space(1))) void*)g,
                                     (__attribute__((address_space(3))) void*)l, 16, 0, 0);
}

// ---------- K0: outv[b,x] = sum_d X[b,d,x] * w[d] ----------
__global__ void k_dotw(const float* __restrict__ X, const float* __restrict__ w,
                       float* __restrict__ outv, int L) {
    int idx = blockIdx.x * 256 + threadIdx.x;
    int b = idx / L, x = idx - b * L;
    const float* Xp = X + (size_t)b * D_ * L + x;
    float acc = 0.f;
#pragma unroll 8
    for (int dd = 0; dd < D_; ++dd) acc += Xp[(size_t)dd * L] * w[dd];
    outv[idx] = acc;
}

// ---------- prep C ----------
__global__ void k_prep_C(const float* __restrict__ C, const float* __restrict__ wmul,
                         short* __restrict__ Ctw, short* __restrict__ Cb16) {
    int b = blockIdx.y, c0 = blockIdx.x * 64;
    __shared__ float Tf[128][65];
    __shared__ float wm[128];
    int t = threadIdx.x;
    if (t < 128) wm[t] = wmul[t];
    const float* Cb = C + (size_t)b * D_ * LC;
#pragma unroll
    for (int i = 0; i < 8; ++i) {
        int idx = t + i * 256;
        int d = idx >> 4, c4 = idx & 15;
        float4 v = *(const float4*)(Cb + (size_t)d * LC + c0 + c4 * 4);
        Tf[d][c4 * 4 + 0] = v.x; Tf[d][c4 * 4 + 1] = v.y;
        Tf[d][c4 * 4 + 2] = v.z; Tf[d][c4 * 4 + 3] = v.w;
        ushort4 cv;
        cv.x = bf16rne(v.x); cv.y = bf16rne(v.y); cv.z = bf16rne(v.z); cv.w = bf16rne(v.w);
        *(ushort4*)(Cb16 + ((size_t)b * D_ + d) * LC + c0 + c4 * 4) = cv;
    }
    __syncthreads();
    int c_l = t & 63, g = t >> 6;
    unsigned short u[32];
#pragma unroll
    for (int j = 0; j < 32; ++j) {
        int d = g * 32 + j;
        u[j] = bf16rne(Tf[d][c_l] * wm[d]);
    }
    short* dst = Ctw + ((size_t)b * LC + c0 + c_l) * D_ + g * 32;
#pragma unroll
    for (int k = 0; k < 4; ++k) *(us8*)(dst + k * 8) = *(const us8*)&u[k * 8];
}

// ---------- prep Q ----------
__global__ void k_prep_Q(const float* __restrict__ Q, short* __restrict__ Qt16,
                         short* __restrict__ Wf) {
    int b = blockIdx.y, q0 = blockIdx.x * 64;
    __shared__ float Tf[128][65];
    int t = threadIdx.x;
    const float* Qb = Q + (size_t)b * D_ * LQ;
#pragma unroll
    for (int i = 0; i < 8; ++i) {
        int idx = t + i * 256;
        int d = idx >> 4, q4 = idx & 15;
        float4 v = *(const float4*)(Qb + (size_t)d * LQ + q0 + q4 * 4);
        Tf[d][q4 * 4 + 0] = v.x; Tf[d][q4 * 4 + 1] = v.y;
        Tf[d][q4 * 4 + 2] = v.z; Tf[d][q4 * 4 + 3] = v.w;
        ushort4 cv;
        cv.x = bf16rne(v.x); cv.y = bf16rne(v.y); cv.z = bf16rne(v.z); cv.w = bf16rne(v.w);
        *(ushort4*)(Wf + ((size_t)b * 256 + d) * LQ + q0 + q4 * 4) = cv;
    }
    __syncthreads();
    int q_l = t & 63, g = t >> 6;
    unsigned short u[32];
#pragma unroll
    for (int j = 0; j < 32; ++j) u[j] = bf16rne(Tf[g * 32 + j][q_l]);
    short* dst = Qt16 + ((size_t)b * LQ + q0 + q_l) * D_ + g * 32;
#pragma unroll
    for (int k = 0; k < 4; ++k) *(us8*)(dst + k * 8) = *(const us8*)&u[k * 8];
}

// ---------- K1: S[c][q] via MFMA, stored fp16; FUSED col-stats (max-shifted) and
// row-SUM partials (zero-shift; |S|<~20 so exp() is fp32-safe). ----------
__global__ __launch_bounds__(256) void k_S_mfma(const short* __restrict__ Ctw,
                                                const short* __restrict__ Qt16,
                                                const float* __restrict__ s0,
                                                const float* __restrict__ s1,
                                                const float* __restrict__ bias,
                                                const int* __restrict__ Cmask,
                                                const int* __restrict__ Qmask,
                                                _Float16* __restrict__ S16,
                                                float* __restrict__ pm,
                                                float* __restrict__ pl,
                                                float* __restrict__ plr) {
    int b = blockIdx.y;
    int cT = blockIdx.x >> 2, qT = blockIdx.x & 3;
    int c0 = cT * 128, q0 = qT * 128;
    int t = threadIdx.x, w = t >> 6, l = t & 63;
    int wm_ = w >> 1, wn = w & 1;
    __shared__ short As[128 * 64];
    __shared__ short Bs[128 * 64];
    f32x4 acc[4][4] = {};
    const short* Arow = Ctw + ((size_t)b * LC + c0) * D_;
    const short* Brow = Qt16 + ((size_t)b * LQ + q0) * D_;
    int lr = l >> 3, sl = l & 7;
    for (int kt = 0; kt < 2; ++kt) {
        __syncthreads();
#pragma unroll
        for (int i = 0; i < 4; ++i) {
            int r = w * 32 + i * 8 + lr;
            int g = sl ^ (r & 7);
            gll16(Arow + (size_t)r * D_ + kt * 64 + g * 8, &As[(w * 32 + i * 8) * 64]);
            gll16(Brow + (size_t)r * D_ + kt * 64 + g * 8, &Bs[(w * 32 + i * 8) * 64]);
        }
        __syncthreads();
#pragma unroll
        for (int ks = 0; ks < 2; ++ks) {
            int kg = ks * 4 + (l >> 4);
            bf16x8 af[4], bfr[4];
#pragma unroll
            for (int ms = 0; ms < 4; ++ms) {
                int m = wm_ * 64 + ms * 16 + (l & 15);
                af[ms] = *(const bf16x8*)&As[m * 64 + (kg ^ (m & 7)) * 8];
            }
#pragma unroll
            for (int ns = 0; ns < 4; ++ns) {
                int n = wn * 64 + ns * 16 + (l & 15);
                bfr[ns] = *(const bf16x8*)&Bs[n * 64 + (kg ^ (n & 7)) * 8];
            }
#pragma unroll
            for (int ms = 0; ms < 4; ++ms)
#pragma unroll
                for (int ns = 0; ns < 4; ++ns)
                    acc[ms][ns] = __builtin_amdgcn_mfma_f32_16x16x32_bf16(af[ms], bfr[ns], acc[ms][ns], 0, 0, 0);
        }
    }
    float bv = bias[0];
    float s0v[16];
    int cmv[16];
#pragma unroll
    for (int ms = 0; ms < 4; ++ms) {
        int cb = c0 + wm_ * 64 + ms * 16 + (l >> 4) * 4;
        float4 sv = *(const float4*)(s0 + b * LC + cb);
        s0v[ms * 4 + 0] = sv.x; s0v[ms * 4 + 1] = sv.y;
        s0v[ms * 4 + 2] = sv.z; s0v[ms * 4 + 3] = sv.w;
        int4 cv = *(const int4*)(Cmask + b * LC + cb);
        cmv[ms * 4 + 0] = cv.x; cmv[ms * 4 + 1] = cv.y;
        cmv[ms * 4 + 2] = cv.z; cmv[ms * 4 + 3] = cv.w;
    }
    float rs_[16];
#pragma unroll
    for (int k = 0; k < 16; ++k) rs_[k] = 0.f;
    __syncthreads();
    float* Mp = (float*)As;               // col-max partials [8][132]
    float* Lp = (float*)Bs;               // col-sum partials [8][132]
    float* Rsf = (float*)As + 2048;       // row-sum halves [2][128]
    int prow = wm_ * 4 + (l >> 4);        // 0..7
#pragma unroll
    for (int ns = 0; ns < 4; ++ns) {
        int qi = wn * 64 + ns * 16 + (l & 15);   // 0..127 within tile
        int q = q0 + qi;
        float s1v = s1[b * LQ + q] + bv;
        int qmn = Qmask[b * LQ + q];
        float vq16[16];
#pragma unroll
        for (int ms = 0; ms < 4; ++ms) {
            int cb = c0 + wm_ * 64 + ms * 16 + (l >> 4) * 4;
#pragma unroll
            for (int r = 0; r < 4; ++r) {
                float vf = acc[ms][ns][r] + s0v[ms * 4 + r] + s1v;
                _Float16 h = (_Float16)vf;
                S16[((size_t)b * LC + cb + r) * LQ + q] = h;
                vq16[ms * 4 + r] = (float)h;
            }
        }
        float mt = NEGINF;
#pragma unroll
        for (int k = 0; k < 16; ++k) mt = fmaxf(mt, cmv[k] ? vq16[k] : NEGINF);
        float st = 0.f;
#pragma unroll
        for (int k = 0; k < 16; ++k) st += cmv[k] ? __expf(vq16[k] - mt) : 0.f;
        Mp[prow * 132 + qi] = mt;
        Lp[prow * 132 + qi] = st;
#pragma unroll
        for (int k = 0; k < 16; ++k) rs_[k] += qmn ? __expf(vq16[k]) : 0.f;
    }
#pragma unroll
    for (int off = 1; off < 16; off <<= 1)
#pragma unroll
        for (int k = 0; k < 16; ++k) rs_[k] += __shfl_xor(rs_[k], off, 64);
    if ((l & 15) == 0) {
#pragma unroll
        for (int ms = 0; ms < 4; ++ms)
#pragma unroll
            for (int r = 0; r < 4; ++r) {
                int cl = wm_ * 64 + ms * 16 + (l >> 4) * 4 + r;
                Rsf[wn * 128 + cl] = rs_[ms * 4 + r];
            }
    }
    __syncthreads();
    if (t < 128) {
        float mm = Mp[t], ll = Lp[t];
#pragma unroll
        for (int g = 1; g < 8; ++g) {
            float m2 = Mp[g * 132 + t], l2 = Lp[g * 132 + t];
            float mn = fmaxf(mm, m2);
            ll = ll * __expf(mm - mn) + l2 * __expf(m2 - mn);
            mm = mn;
        }
        size_t o = ((size_t)cT * B_ + b) * LQ + q0 + t;
        pm[o] = mm; pl[o] = ll;
        size_t orow = ((size_t)qT * B_ + b) * LC + c0 + t;
        plr[orow] = Rsf[t] + Rsf[128 + t];
    }
}

// ---------- K3: combine partials ----------
__global__ void k_comb(const float* __restrict__ pm, const float* __restrict__ pl,
                       const float* __restrict__ plr,
                       float* __restrict__ colmax, float* __restrict__ colsum,
                       float* __restrict__ rowsum) {
    int bx = blockIdx.x;
    if (bx < (B_ * LQ) / 256) {
        int idx = bx * 256 + threadIdx.x;       // b*LQ + q
        float m = NEGINF, l = 0.f;
#pragma unroll
        for (int ch = 0; ch < CCH; ++ch) {
            float m2 = pm[(size_t)ch * B_ * LQ + idx];
            float l2 = pl[(size_t)ch * B_ * LQ + idx];
            float mn = fmaxf(m, m2);
            l = l * __expf(m - mn) + l2 * __expf(m2 - mn);
            m = mn;
        }
        colmax[idx] = m; colsum[idx] = l;
    } else {
        int idx = (bx - (B_ * LQ) / 256) * 256 + threadIdx.x;  // b*LC + c
        float s = 0.f;
#pragma unroll
        for (int ch = 0; ch < RCH; ++ch) s += plr[(size_t)ch * B_ * LC + idx];
        rowsum[idx] = s;
    }
}

// ---------- K5: V2 GEMM (reads raw S once per kt for the col-exp B operand) ----------
__global__ __launch_bounds__(256) void k_V2_mfma(const short* __restrict__ Cb16,
                                                 const _Float16* __restrict__ S16,
                                                 const int* __restrict__ Cmask,
                                                 const float* __restrict__ colmax,
                                                 const float* __restrict__ colsum,
                                                 short* __restrict__ Wf) {
    int b = blockIdx.y;
    int q0 = blockIdx.x * 64;
    int t = threadIdx.x, w = t >> 6, l = t & 63;
    __shared__ short As[128 * 64];
    __shared__ short Bs[64 * 72];
    f32x4 acc[2][4] = {};
    const short* Arow = Cb16 + (size_t)b * D_ * LC;
    int lr = l >> 3, sl = l & 7;
    float cmx[16];
#pragma unroll
    for (int j2 = 0; j2 < 4; ++j2)
        *(float4*)&cmx[j2 * 4] = *(const float4*)(colmax + b * LQ + q0 + w * 16 + j2 * 4);
    const _Float16* Sq = S16 + (size_t)b * LC * LQ + q0 + w * 16;
    const int* cmb = Cmask + b * LC;

    for (int kt = 0; kt < 32; ++kt) {
        int ck = kt * 64;
        __builtin_amdgcn_s_barrier();        // prev iter's LDS reads all consumed
        __builtin_amdgcn_sched_barrier(0);
#pragma unroll
        for (int i = 0; i < 4; ++i) {
            int r = w * 32 + i * 8 + lr;
            int g = sl ^ (r & 7);
            gll16(Arow + (size_t)r * LC + ck + g * 8, &As[(w * 32 + i * 8) * 64]);
        }
        {
            int c = ck + l;
            float cmf = (float)cmb[c];
            const _Float16* sp = Sq + (size_t)c * LQ;
            f16x8 v0 = *(const f16x8*)sp;
            f16x8 v1 = *(const f16x8*)(sp + 8);
#pragma unroll
            for (int j = 0; j < 8; ++j)
                Bs[(w * 16 + j) * 72 + l] = (short)bf16rne(cmf * __expf((float)v0[j] - cmx[j]));
#pragma unroll
            for (int j = 0; j < 8; ++j)
                Bs[(w * 16 + 8 + j) * 72 + l] = (short)bf16rne(cmf * __expf((float)v1[j] - cmx[8 + j]));
        }
        asm volatile("s_waitcnt vmcnt(0) lgkmcnt(0)" ::: "memory");
        __builtin_amdgcn_s_barrier();
        __builtin_amdgcn_sched_barrier(0);
#pragma unroll
        for (int ks = 0; ks < 2; ++ks) {
            int kg = ks * 4 + (l >> 4);
            bf16x8 af[2], bfr[4];
#pragma unroll
            for (int ms = 0; ms < 2; ++ms) {
                int m = w * 32 + ms * 16 + (l & 15);
                af[ms] = *(const bf16x8*)&As[m * 64 + (kg ^ (m & 7)) * 8];
            }
#pragma unroll
            for (int ns = 0; ns < 4; ++ns) {
                int n = ns * 16 + (l & 15);
                bfr[ns] = *(const bf16x8*)&Bs[n * 72 + kg * 8];
            }
#pragma unroll
            for (int ms = 0; ms < 2; ++ms)
#pragma unroll
                for (int ns = 0; ns < 4; ++ns)
                    acc[ms][ns] = __builtin_amdgcn_mfma_f32_16x16x32_bf16(af[ms], bfr[ns], acc[ms][ns], 0, 0, 0);
        }
    }
#pragma unroll
    for (int ms = 0; ms < 2; ++ms)
#pragma unroll
        for (int ns = 0; ns < 4; ++ns) {
            int q = q0 + ns * 16 + (l & 15);
            float csi = 1.0f / colsum[b * LQ + q];
#pragma unroll
            for (int r = 0; r < 4; ++r) {
                int dd = w * 32 + ms * 16 + (l >> 4) * 4 + r;
                Wf[((size_t)b * 256 + 128 + dd) * LQ + q] = (short)bf16rne(acc[ms][ns][r] * csi);
            }
        }
}

// ---------- K6: OUT^T GEMM, A-DIRECT: no As LDS at all — A fragments are per-lane
// 16B loads straight from Wf (8.4 MB total, L2/L3-resident; staging cache-fit data
// is pure overhead). B = P1 on the fly from raw S16 (reg-staged 2-deep, exp,
// ds_write to single-buffered 16 KB Bs). LDS 16 KB + launch_bounds(512,4)
// (<=128 regs/wave incl. AGPR acc) -> 2 blocks/CU resident. ----------
__global__ __launch_bounds__(512, 4) void k_out_mfma(const _Float16* __restrict__ S16,
                                                     const short* __restrict__ Wf,
                                                     const float* __restrict__ C,
                                                     const int* __restrict__ Qmask,
                                                     const float* __restrict__ rowsum,
                                                     float* __restrict__ out) {
    int b = blockIdx.y;
    int c0 = blockIdx.x * 128;
    int t = threadIdx.x, w = t >> 6, l = t & 63;
    int wn = w & 3, wc = w >> 2;            // wave tile: n = wn*64.., c = wc*64..
    __shared__ short Bs[128 * 64];           // P1 rows (c), 16 KB total LDS
    f32x4 acc[4][4] = {};
    const short* Arow = Wf + (size_t)b * 256 * LQ;
    const _Float16* Brow = S16 + ((size_t)b * LC + c0) * LQ;
    int lr = l >> 3, sl = l & 7;
    int g = sl ^ lr;                         // staging swizzle (row&7 == lr)
    // B thread-fixed rows + their 1/rowsum (constant across kt)
    int r0 = w * 16 + lr, r1 = r0 + 8;
    float ri0 = 1.0f / rowsum[b * LC + c0 + r0];
    float ri1 = 1.0f / rowsum[b * LC + c0 + r1];
    // Qmask bits for this thread's q-slots: bit (kt*8+j) = Qmask[kt*64 + g*8 + j]
    unsigned long long qbits = 0ull;
#pragma unroll
    for (int kt = 0; kt < 8; ++kt) {
        const int* qp = Qmask + b * LQ + kt * 64 + g * 8;
        int4 qa = *(const int4*)qp;
        int4 qb = *(const int4*)(qp + 4);
        unsigned bits = (qa.x ? 1u : 0u) | (qa.y ? 2u : 0u) | (qa.z ? 4u : 0u) | (qa.w ? 8u : 0u)
                      | (qb.x ? 16u : 0u) | (qb.y ? 32u : 0u) | (qb.z ? 64u : 0u) | (qb.w ? 128u : 0u);
        qbits |= (unsigned long long)bits << (kt * 8);
    }

#define LOAD_B(v0_, v1_, kt)                                                      \
    v0_ = *(const f16x8*)(Brow + (size_t)r0 * LQ + (kt) * 64 + g * 8);            \
    v1_ = *(const f16x8*)(Brow + (size_t)r1 * LQ + (kt) * 64 + g * 8);

    f16x8 bA0, bA1, bB0, bB1;                // two tiles of B regs in flight
    LOAD_B(bA0, bA1, 0);
    LOAD_B(bB0, bB1, 1);
    for (int kt = 0; kt < 8; ++kt) {
        // build P1 tile in LDS from regs: p = qm ? exp(S)*ri : 0
        // (single-buffer safe: all Bs reads of iter kt-1 completed before every
        //  wave passed the end-of-iter barrier)
        {
            f16x8 v0 = (kt & 1) ? bB0 : bA0;
            f16x8 v1 = (kt & 1) ? bB1 : bA1;
            unsigned bits = (unsigned)(qbits >> (kt * 8)) & 0xffu;
            unsigned short p0[8], p1[8];
#pragma unroll
            for (int j = 0; j < 8; ++j)
                p0[j] = (bits >> j) & 1u ? bf16rne(__expf((float)v0[j]) * ri0) : (unsigned short)0;
#pragma unroll
            for (int j = 0; j < 8; ++j)
                p1[j] = (bits >> j) & 1u ? bf16rne(__expf((float)v1[j]) * ri1) : (unsigned short)0;
            *(us8*)&Bs[r0 * 64 + sl * 8] = *(const us8*)&p0[0];
            *(us8*)&Bs[r1 * 64 + sl * 8] = *(const us8*)&p1[0];
        }
        asm volatile("s_waitcnt lgkmcnt(0)" ::: "memory");
        __builtin_amdgcn_s_barrier();
        __builtin_amdgcn_sched_barrier(0);
#pragma unroll
        for (int ks = 0; ks < 2; ++ks) {
            int kg = ks * 4 + (l >> 4);
            bf16x8 af[4], bfr[4];
#pragma unroll
            for (int ms = 0; ms < 4; ++ms) {
                int m = wn * 64 + ms * 16 + (l & 15);
                af[ms] = *(const bf16x8*)(Arow + (size_t)m * LQ + kt * 64 + kg * 8);  // A direct from L2/L3
            }
#pragma unroll
            for (int ns = 0; ns < 4; ++ns) {
                int cc = wc * 64 + ns * 16 + (l & 15);
                bfr[ns] = *(const bf16x8*)&Bs[cc * 64 + (kg ^ (cc & 7)) * 8];
            }
#pragma unroll
            for (int ms = 0; ms < 4; ++ms)
#pragma unroll
                for (int ns = 0; ns < 4; ++ns)
                    acc[ms][ns] = __builtin_amdgcn_mfma_f32_16x16x32_bf16(af[ms], bfr[ns], acc[ms][ns], 0, 0, 0);
        }
        __builtin_amdgcn_s_barrier();        // all waves done reading Bs
        __builtin_amdgcn_sched_barrier(0);
        if (kt < 6) {
            if (kt & 1) { LOAD_B(bB0, bB1, kt + 2); }
            else        { LOAD_B(bA0, bA1, kt + 2); }
        }
    }
#undef LOAD_B
#pragma unroll
    for (int ms = 0; ms < 4; ++ms) {
        int nb = wn * 64 + ms * 16 + (l >> 4) * 4;
#pragma unroll
        for (int ns = 0; ns < 4; ++ns) {
            int c = c0 + wc * 64 + ns * 16 + (l & 15);
#pragma unroll
            for (int r = 0; r < 4; ++r) {
                int n = nb + r;
                float a = acc[ms][ns][r];
                if (n < 128) {
                    float cv = C[((size_t)b * D_ + n) * LC + c];
                    out[((size_t)b * 512 + n) * LC + c] = cv;          // plane 0: Ct
                    out[((size_t)b * 512 + 128 + n) * LC + c] = a;     // plane 1: A
                    out[((size_t)b * 512 + 256 + n) * LC + c] = cv * a;// plane 2: Ct*A
                } else {
                    int dd = n - 128;
                    float cv = C[((size_t)b * D_ + dd) * LC + c];
                    out[((size_t)b * 512 + 384 + dd) * LC + c] = cv * a;// plane 3: Ct*Bm
                }
            }
        }
    }
}

extern "C" void kernel_launch(void* const* d_in, const int* in_sizes, int n_in,
                              void* d_out, int out_size, void* d_ws, size_t ws_size,
                              hipStream_t stream) {
    const float* C     = (const float*)d_in[0];
    const float* Q     = (const float*)d_in[1];
    const int*   Cmask = (const int*)d_in[2];
    const int*   Qmask = (const int*)d_in[3];
    const float* w_c   = (const float*)d_in[4];
    const float* w_q   = (const float*)d_in[5];
    const float* w_mul = (const float*)d_in[6];
    const float* bias  = (const float*)d_in[7];
    float* out = (float*)d_out;

    _Float16* S16 = (_Float16*)d_ws;                      // B*LC*LQ fp16  = 67.1 MB (stays RAW)
    short* Cb16 = (short*)(S16 + (size_t)B_ * LC * LQ);   // B*D*LC bf16   = 16.8 MB
    short* Ctw  = Cb16 + (size_t)B_ * D_ * LC;            // B*LC*D bf16   = 16.8 MB
    short* Qt16 = Ctw + (size_t)B_ * LC * D_;             // B*LQ*D bf16   =  4.2 MB
    short* Wf   = Qt16 + (size_t)B_ * LQ * D_;            // B*256*LQ bf16 =  8.4 MB
    float* s0     = (float*)(Wf + (size_t)B_ * 256 * LQ); // B*LC
    float* s1     = s0 + B_ * LC;                         // B*LQ
    float* colmax = s1 + B_ * LQ;                         // B*LQ
    float* colsum = colmax + B_ * LQ;                     // B*LQ
    float* rowsum = colsum + B_ * LQ;                     // B*LC
    float* pm     = rowsum + B_ * LC;                     // CCH*B*LQ = 1 MB
    float* pl     = pm + (size_t)CCH * B_ * LQ;           // CCH*B*LQ = 1 MB
    float* plr    = pl + (size_t)CCH * B_ * LQ;           // RCH*B*LC = 1 MB

    hipLaunchKernelGGL(k_dotw, dim3(B_ * LC / 256), dim3(256), 0, stream, C, w_c, s0, LC);
    hipLaunchKernelGGL(k_dotw, dim3(B_ * LQ / 256), dim3(256), 0, stream, Q, w_q, s1, LQ);
    hipLaunchKernelGGL(k_prep_C, dim3(LC / 64, B_), dim3(256), 0, stream, C, w_mul, Ctw, Cb16);
    hipLaunchKernelGGL(k_prep_Q, dim3(LQ / 64, B_), dim3(256), 0, stream, Q, Qt16, Wf);
    // k_S emits S16 + col partials (pm/pl) + row-sum partials (plr)
    hipLaunchKernelGGL(k_S_mfma, dim3((LC / 128) * (LQ / 128), B_), dim3(256), 0, stream,
                       Ctw, Qt16, s0, s1, bias, Cmask, Qmask, S16, pm, pl, plr);
    hipLaunchKernelGGL(k_comb, dim3((B_ * LQ + B_ * LC) / 256), dim3(256), 0, stream,
                       pm, pl, plr, colmax, colsum, rowsum);
    // V2 GEMM (reads raw S; no P1 writeback)
    hipLaunchKernelGGL(k_V2_mfma, dim3(LQ / 64, B_), dim3(256), 0, stream,
                       Cb16, S16, Cmask, colmax, colsum, Wf);
    // OUT GEMM computes row-softmax on the fly from raw S16, A direct from cache
    hipLaunchKernelGGL(k_out_mfma, dim3(LC / 128, B_), dim3(512), 0, stream,
                       S16, Wf, C, Qmask, rowsum, out);
}

// Round 14
// 371.961 us; speedup vs baseline: 1.0365x; 1.0365x over previous
//
#include <hip/hip_runtime.h>

#define B_ 32
#define D_ 128
#define LC 2048
#define LQ 512
#define CCH 16   // col-partials count == LC/128 (one per k_S c-tile)
#define RCH 4    // row-partials count == LQ/128 (one per k_S q-tile)

#define NEGINF (-3.0e38f)

typedef __attribute__((ext_vector_type(8))) short bf16x8;
typedef __attribute__((ext_vector_type(4))) float f32x4;
typedef __attribute__((ext_vector_type(8))) unsigned short us8;
typedef __attribute__((ext_vector_type(8))) _Float16 f16x8;

__device__ __forceinline__ unsigned short bf16rne(float x) {
    unsigned int u = __float_as_uint(x);
    u = (u + 0x7FFFu + ((u >> 16) & 1u)) >> 16;
    return (unsigned short)u;
}

__device__ __forceinline__ void gll16(const void* g, void* l) {
    __builtin_amdgcn_global_load_lds((const __attribute__((address_space(1))) void*)g,
                                     (__attribute__((address_space(3))) void*)l, 16, 0, 0);
}

// ---------- K0: outv[b,x] = sum_d X[b,d,x] * w[d] ----------
__global__ void k_dotw(const float* __restrict__ X, const float* __restrict__ w,
                       float* __restrict__ outv, int L) {
    int idx = blockIdx.x * 256 + threadIdx.x;
    int b = idx / L, x = idx - b * L;
    const float* Xp = X + (size_t)b * D_ * L + x;
    float acc = 0.f;
#pragma unroll 8
    for (int dd = 0; dd < D_; ++dd) acc += Xp[(size_t)dd * L] * w[dd];
    outv[idx] = acc;
}

// ---------- prep C ----------
__global__ void k_prep_C(const float* __restrict__ C, const float* __restrict__ wmul,
                         short* __restrict__ Ctw, short* __restrict__ Cb16) {
    int b = blockIdx.y, c0 = blockIdx.x * 64;
    __shared__ float Tf[128][65];
    __shared__ float wm[128];
    int t = threadIdx.x;
    if (t < 128) wm[t] = wmul[t];
    const float* Cb = C + (size_t)b * D_ * LC;
#pragma unroll
    for (int i = 0; i < 8; ++i) {
        int idx = t + i * 256;
        int d = idx >> 4, c4 = idx & 15;
        float4 v = *(const float4*)(Cb + (size_t)d * LC + c0 + c4 * 4);
        Tf[d][c4 * 4 + 0] = v.x; Tf[d][c4 * 4 + 1] = v.y;
        Tf[d][c4 * 4 + 2] = v.z; Tf[d][c4 * 4 + 3] = v.w;
        ushort4 cv;
        cv.x = bf16rne(v.x); cv.y = bf16rne(v.y); cv.z = bf16rne(v.z); cv.w = bf16rne(v.w);
        *(ushort4*)(Cb16 + ((size_t)b * D_ + d) * LC + c0 + c4 * 4) = cv;
    }
    __syncthreads();
    int c_l = t & 63, g = t >> 6;
    unsigned short u[32];
#pragma unroll
    for (int j = 0; j < 32; ++j) {
        int d = g * 32 + j;
        u[j] = bf16rne(Tf[d][c_l] * wm[d]);
    }
    short* dst = Ctw + ((size_t)b * LC + c0 + c_l) * D_ + g * 32;
#pragma unroll
    for (int k = 0; k < 4; ++k) *(us8*)(dst + k * 8) = *(const us8*)&u[k * 8];
}

// ---------- prep Q ----------
__global__ void k_prep_Q(const float* __restrict__ Q, short* __restrict__ Qt16,
                         short* __restrict__ Wf) {
    int b = blockIdx.y, q0 = blockIdx.x * 64;
    __shared__ float Tf[128][65];
    int t = threadIdx.x;
    const float* Qb = Q + (size_t)b * D_ * LQ;
#pragma unroll
    for (int i = 0; i < 8; ++i) {
        int idx = t + i * 256;
        int d = idx >> 4, q4 = idx & 15;
        float4 v = *(const float4*)(Qb + (size_t)d * LQ + q0 + q4 * 4);
        Tf[d][q4 * 4 + 0] = v.x; Tf[d][q4 * 4 + 1] = v.y;
        Tf[d][q4 * 4 + 2] = v.z; Tf[d][q4 * 4 + 3] = v.w;
        ushort4 cv;
        cv.x = bf16rne(v.x); cv.y = bf16rne(v.y); cv.z = bf16rne(v.z); cv.w = bf16rne(v.w);
        *(ushort4*)(Wf + ((size_t)b * 256 + d) * LQ + q0 + q4 * 4) = cv;
    }
    __syncthreads();
    int q_l = t & 63, g = t >> 6;
    unsigned short u[32];
#pragma unroll
    for (int j = 0; j < 32; ++j) u[j] = bf16rne(Tf[g * 32 + j][q_l]);
    short* dst = Qt16 + ((size_t)b * LQ + q0 + q_l) * D_ + g * 32;
#pragma unroll
    for (int k = 0; k < 4; ++k) *(us8*)(dst + k * 8) = *(const us8*)&u[k * 8];
}

// ---------- K1: S[c][q] via MFMA, stored fp16; FUSED col-stats (max-shifted) and
// row-SUM partials (zero-shift; |S|<~20 so exp() is fp32-safe). ----------
__global__ __launch_bounds__(256) void k_S_mfma(const short* __restrict__ Ctw,
                                                const short* __restrict__ Qt16,
                                                const float* __restrict__ s0,
                                                const float* __restrict__ s1,
                                                const float* __restrict__ bias,
                                                const int* __restrict__ Cmask,
                                                const int* __restrict__ Qmask,
                                                _Float16* __restrict__ S16,
                                                float* __restrict__ pm,
                                                float* __restrict__ pl,
                                                float* __restrict__ plr) {
    int b = blockIdx.y;
    int cT = blockIdx.x >> 2, qT = blockIdx.x & 3;
    int c0 = cT * 128, q0 = qT * 128;
    int t = threadIdx.x, w = t >> 6, l = t & 63;
    int wm_ = w >> 1, wn = w & 1;
    __shared__ short As[128 * 64];
    __shared__ short Bs[128 * 64];
    f32x4 acc[4][4] = {};
    const short* Arow = Ctw + ((size_t)b * LC + c0) * D_;
    const short* Brow = Qt16 + ((size_t)b * LQ + q0) * D_;
    int lr = l >> 3, sl = l & 7;
    for (int kt = 0; kt < 2; ++kt) {
        __syncthreads();
#pragma unroll
        for (int i = 0; i < 4; ++i) {
            int r = w * 32 + i * 8 + lr;
            int g = sl ^ (r & 7);
            gll16(Arow + (size_t)r * D_ + kt * 64 + g * 8, &As[(w * 32 + i * 8) * 64]);
            gll16(Brow + (size_t)r * D_ + kt * 64 + g * 8, &Bs[(w * 32 + i * 8) * 64]);
        }
        __syncthreads();
#pragma unroll
        for (int ks = 0; ks < 2; ++ks) {
            int kg = ks * 4 + (l >> 4);
            bf16x8 af[4], bfr[4];
#pragma unroll
            for (int ms = 0; ms < 4; ++ms) {
                int m = wm_ * 64 + ms * 16 + (l & 15);
                af[ms] = *(const bf16x8*)&As[m * 64 + (kg ^ (m & 7)) * 8];
            }
#pragma unroll
            for (int ns = 0; ns < 4; ++ns) {
                int n = wn * 64 + ns * 16 + (l & 15);
                bfr[ns] = *(const bf16x8*)&Bs[n * 64 + (kg ^ (n & 7)) * 8];
            }
#pragma unroll
            for (int ms = 0; ms < 4; ++ms)
#pragma unroll
                for (int ns = 0; ns < 4; ++ns)
                    acc[ms][ns] = __builtin_amdgcn_mfma_f32_16x16x32_bf16(af[ms], bfr[ns], acc[ms][ns], 0, 0, 0);
        }
    }
    float bv = bias[0];
    float s0v[16];
    int cmv[16];
#pragma unroll
    for (int ms = 0; ms < 4; ++ms) {
        int cb = c0 + wm_ * 64 + ms * 16 + (l >> 4) * 4;
        float4 sv = *(const float4*)(s0 + b * LC + cb);
        s0v[ms * 4 + 0] = sv.x; s0v[ms * 4 + 1] = sv.y;
        s0v[ms * 4 + 2] = sv.z; s0v[ms * 4 + 3] = sv.w;
        int4 cv = *(const int4*)(Cmask + b * LC + cb);
        cmv[ms * 4 + 0] = cv.x; cmv[ms * 4 + 1] = cv.y;
        cmv[ms * 4 + 2] = cv.z; cmv[ms * 4 + 3] = cv.w;
    }
    float rs_[16];
#pragma unroll
    for (int k = 0; k < 16; ++k) rs_[k] = 0.f;
    __syncthreads();
    float* Mp = (float*)As;               // col-max partials [8][132]
    float* Lp = (float*)Bs;               // col-sum partials [8][132]
    float* Rsf = (float*)As + 2048;       // row-sum halves [2][128]
    int prow = wm_ * 4 + (l >> 4);        // 0..7
#pragma unroll
    for (int ns = 0; ns < 4; ++ns) {
        int qi = wn * 64 + ns * 16 + (l & 15);   // 0..127 within tile
        int q = q0 + qi;
        float s1v = s1[b * LQ + q] + bv;
        int qmn = Qmask[b * LQ + q];
        float vq16[16];
#pragma unroll
        for (int ms = 0; ms < 4; ++ms) {
            int cb = c0 + wm_ * 64 + ms * 16 + (l >> 4) * 4;
#pragma unroll
            for (int r = 0; r < 4; ++r) {
                float vf = acc[ms][ns][r] + s0v[ms * 4 + r] + s1v;
                _Float16 h = (_Float16)vf;
                S16[((size_t)b * LC + cb + r) * LQ + q] = h;
                vq16[ms * 4 + r] = (float)h;
            }
        }
        float mt = NEGINF;
#pragma unroll
        for (int k = 0; k < 16; ++k) mt = fmaxf(mt, cmv[k] ? vq16[k] : NEGINF);
        float st = 0.f;
#pragma unroll
        for (int k = 0; k < 16; ++k) st += cmv[k] ? __expf(vq16[k] - mt) : 0.f;
        Mp[prow * 132 + qi] = mt;
        Lp[prow * 132 + qi] = st;
#pragma unroll
        for (int k = 0; k < 16; ++k) rs_[k] += qmn ? __expf(vq16[k]) : 0.f;
    }
#pragma unroll
    for (int off = 1; off < 16; off <<= 1)
#pragma unroll
        for (int k = 0; k < 16; ++k) rs_[k] += __shfl_xor(rs_[k], off, 64);
    if ((l & 15) == 0) {
#pragma unroll
        for (int ms = 0; ms < 4; ++ms)
#pragma unroll
            for (int r = 0; r < 4; ++r) {
                int cl = wm_ * 64 + ms * 16 + (l >> 4) * 4 + r;
                Rsf[wn * 128 + cl] = rs_[ms * 4 + r];
            }
    }
    __syncthreads();
    if (t < 128) {
        float mm = Mp[t], ll = Lp[t];
#pragma unroll
        for (int g = 1; g < 8; ++g) {
            float m2 = Mp[g * 132 + t], l2 = Lp[g * 132 + t];
            float mn = fmaxf(mm, m2);
            ll = ll * __expf(mm - mn) + l2 * __expf(m2 - mn);
            mm = mn;
        }
        size_t o = ((size_t)cT * B_ + b) * LQ + q0 + t;
        pm[o] = mm; pl[o] = ll;
        size_t orow = ((size_t)qT * B_ + b) * LC + c0 + t;
        plr[orow] = Rsf[t] + Rsf[128 + t];
    }
}

// ---------- K3: combine partials ----------
__global__ void k_comb(const float* __restrict__ pm, const float* __restrict__ pl,
                       const float* __restrict__ plr,
                       float* __restrict__ colmax, float* __restrict__ colsum,
                       float* __restrict__ rowsum) {
    int bx = blockIdx.x;
    if (bx < (B_ * LQ) / 256) {
        int idx = bx * 256 + threadIdx.x;       // b*LQ + q
        float m = NEGINF, l = 0.f;
#pragma unroll
        for (int ch = 0; ch < CCH; ++ch) {
            float m2 = pm[(size_t)ch * B_ * LQ + idx];
            float l2 = pl[(size_t)ch * B_ * LQ + idx];
            float mn = fmaxf(m, m2);
            l = l * __expf(m - mn) + l2 * __expf(m2 - mn);
            m = mn;
        }
        colmax[idx] = m; colsum[idx] = l;
    } else {
        int idx = (bx - (B_ * LQ) / 256) * 256 + threadIdx.x;  // b*LC + c
        float s = 0.f;
#pragma unroll
        for (int ch = 0; ch < RCH; ++ch) s += plr[(size_t)ch * B_ * LC + idx];
        rowsum[idx] = s;
    }
}

// ---------- K5: V2 GEMM, WAVE-GROUP SPLIT: 512 threads, 2 groups of 4 waves.
// Group g accumulates kt in [16g, 16g+16) into its own As/Bs; cross-group fp32
// reduce via LDS at the end (group 0 parks acc, group 1 adds + writes Wf). ----------
__global__ __launch_bounds__(512) void k_V2_mfma(const short* __restrict__ Cb16,
                                                 const _Float16* __restrict__ S16,
                                                 const int* __restrict__ Cmask,
                                                 const float* __restrict__ colmax,
                                                 const float* __restrict__ colsum,
                                                 short* __restrict__ Wf) {
    int b = blockIdx.y;
    int q0 = blockIdx.x * 64;
    int t = threadIdx.x;
    int w8 = t >> 6, l = t & 63;
    int gp = w8 >> 2, w = w8 & 3;            // group (c-half), wave-in-group
    __shared__ short As[2][128 * 64];         // 2 x 16 KB
    __shared__ short Bs[2][64 * 72];          // 2 x 9 KB  -> 50 KB total
    f32x4 acc[2][4] = {};
    const short* Arow = Cb16 + (size_t)b * D_ * LC;
    int lr = l >> 3, sl = l & 7;
    float cmx[16];
#pragma unroll
    for (int j2 = 0; j2 < 4; ++j2)
        *(float4*)&cmx[j2 * 4] = *(const float4*)(colmax + b * LQ + q0 + w * 16 + j2 * 4);
    const _Float16* Sq = S16 + (size_t)b * LC * LQ + q0 + w * 16;
    const int* cmb = Cmask + b * LC;

    for (int it = 0; it < 16; ++it) {
        int ck = (gp * 16 + it) * 64;
        __builtin_amdgcn_s_barrier();        // prev iter's LDS reads all consumed (both groups)
        __builtin_amdgcn_sched_barrier(0);
#pragma unroll
        for (int i = 0; i < 4; ++i) {
            int r = w * 32 + i * 8 + lr;
            int g = sl ^ (r & 7);
            gll16(Arow + (size_t)r * LC + ck + g * 8, &As[gp][(w * 32 + i * 8) * 64]);
        }
        {
            int c = ck + l;
            float cmf = (float)cmb[c];
            const _Float16* sp = Sq + (size_t)c * LQ;
            f16x8 v0 = *(const f16x8*)sp;
            f16x8 v1 = *(const f16x8*)(sp + 8);
#pragma unroll
            for (int j = 0; j < 8; ++j)
                Bs[gp][(w * 16 + j) * 72 + l] = (short)bf16rne(cmf * __expf((float)v0[j] - cmx[j]));
#pragma unroll
            for (int j = 0; j < 8; ++j)
                Bs[gp][(w * 16 + 8 + j) * 72 + l] = (short)bf16rne(cmf * __expf((float)v1[j] - cmx[8 + j]));
        }
        asm volatile("s_waitcnt vmcnt(0) lgkmcnt(0)" ::: "memory");
        __builtin_amdgcn_s_barrier();
        __builtin_amdgcn_sched_barrier(0);
#pragma unroll
        for (int ks = 0; ks < 2; ++ks) {
            int kg = ks * 4 + (l >> 4);
            bf16x8 af[2], bfr[4];
#pragma unroll
            for (int ms = 0; ms < 2; ++ms) {
                int m = w * 32 + ms * 16 + (l & 15);
                af[ms] = *(const bf16x8*)&As[gp][m * 64 + (kg ^ (m & 7)) * 8];
            }
#pragma unroll
            for (int ns = 0; ns < 4; ++ns) {
                int n = ns * 16 + (l & 15);
                bfr[ns] = *(const bf16x8*)&Bs[gp][n * 72 + kg * 8];
            }
#pragma unroll
            for (int ms = 0; ms < 2; ++ms)
#pragma unroll
                for (int ns = 0; ns < 4; ++ns)
                    acc[ms][ns] = __builtin_amdgcn_mfma_f32_16x16x32_bf16(af[ms], bfr[ns], acc[ms][ns], 0, 0, 0);
        }
    }
    // cross-group reduce: Rbuf[dd][ql] (128x64 fp32 = 32 KB) overlays dead As
    __syncthreads();
    float* Rbuf = (float*)&As[0][0];
    if (gp == 0) {
#pragma unroll
        for (int ms = 0; ms < 2; ++ms)
#pragma unroll
            for (int ns = 0; ns < 4; ++ns) {
                int ql = ns * 16 + (l & 15);
#pragma unroll
                for (int r = 0; r < 4; ++r) {
                    int dd = w * 32 + ms * 16 + (l >> 4) * 4 + r;
                    Rbuf[dd * 64 + ql] = acc[ms][ns][r];
                }
            }
    }
    __syncthreads();
    if (gp == 1) {
#pragma unroll
        for (int ms = 0; ms < 2; ++ms)
#pragma unroll
            for (int ns = 0; ns < 4; ++ns) {
                int ql = ns * 16 + (l & 15);
                int q = q0 + ql;
                float csi = 1.0f / colsum[b * LQ + q];
#pragma unroll
                for (int r = 0; r < 4; ++r) {
                    int dd = w * 32 + ms * 16 + (l >> 4) * 4 + r;
                    float v = acc[ms][ns][r] + Rbuf[dd * 64 + ql];
                    Wf[((size_t)b * 256 + 128 + dd) * LQ + q] = (short)bf16rne(v * csi);
                }
            }
    }
}

// ---------- K6: OUT^T GEMM (round-11 proven form): A(Wf) gll16 double-buffered;
// B = P1 on the fly from raw S16 (reg-staged 2-deep, exp, ds_write to
// single-buffered 16 KB Bs). LDS 80 KB. ----------
__global__ __launch_bounds__(512) void k_out_mfma(const _Float16* __restrict__ S16,
                                                  const short* __restrict__ Wf,
                                                  const float* __restrict__ C,
                                                  const int* __restrict__ Qmask,
                                                  const float* __restrict__ rowsum,
                                                  float* __restrict__ out) {
    int b = blockIdx.y;
    int c0 = blockIdx.x * 128;
    int t = threadIdx.x, w = t >> 6, l = t & 63;
    int wn = w & 3, wc = w >> 2;            // wave tile: n = wn*64.., c = wc*64..
    __shared__ short As[2 * 256 * 64];       // Wf rows (n), 2 x 32 KB
    __shared__ short Bs[128 * 64];           // P1 rows (c), 16 KB  -> 80 KB total
    f32x4 acc[4][4] = {};
    const short* Arow = Wf + (size_t)b * 256 * LQ;
    const _Float16* Brow = S16 + ((size_t)b * LC + c0) * LQ;
    int lr = l >> 3, sl = l & 7;
    int g = sl ^ lr;                         // staging swizzle (row&7 == lr)
    // B thread-fixed rows + their 1/rowsum (constant across kt)
    int r0 = w * 16 + lr, r1 = r0 + 8;
    float ri0 = 1.0f / rowsum[b * LC + c0 + r0];
    float ri1 = 1.0f / rowsum[b * LC + c0 + r1];
    // Qmask bits for this thread's q-slots: bit (kt*8+j) = Qmask[kt*64 + g*8 + j]
    unsigned long long qbits = 0ull;
#pragma unroll
    for (int kt = 0; kt < 8; ++kt) {
        const int* qp = Qmask + b * LQ + kt * 64 + g * 8;
        int4 qa = *(const int4*)qp;
        int4 qb = *(const int4*)(qp + 4);
        unsigned bits = (qa.x ? 1u : 0u) | (qa.y ? 2u : 0u) | (qa.z ? 4u : 0u) | (qa.w ? 8u : 0u)
                      | (qb.x ? 16u : 0u) | (qb.y ? 32u : 0u) | (qb.z ? 64u : 0u) | (qb.w ? 128u : 0u);
        qbits |= (unsigned long long)bits << (kt * 8);
    }

#define STAGE_A(p, kt)                                                            \
    {                                                                             \
        short* Ad = As + (p) * (256 * 64);                                        \
        _Pragma("unroll")                                                         \
        for (int i = 0; i < 4; ++i) {                                             \
            int r = w * 32 + i * 8 + lr;                                          \
            gll16(Arow + (size_t)r * LQ + (kt) * 64 + g * 8,                      \
                  &Ad[(w * 32 + i * 8) * 64]);                                    \
        }                                                                         \
    }
#define LOAD_B(v0_, v1_, kt)                                                      \
    v0_ = *(const f16x8*)(Brow + (size_t)r0 * LQ + (kt) * 64 + g * 8);            \
    v1_ = *(const f16x8*)(Brow + (size_t)r1 * LQ + (kt) * 64 + g * 8);

    f16x8 bA0, bA1, bB0, bB1;                // two tiles of B regs in flight
    LOAD_B(bA0, bA1, 0);
    STAGE_A(0, 0);
    LOAD_B(bB0, bB1, 1);
    STAGE_A(1, 1);
    __builtin_amdgcn_sched_barrier(0);
    int cur = 0;
    for (int kt = 0; kt < 8; ++kt) {
        if (kt < 7) asm volatile("s_waitcnt vmcnt(6)" ::: "memory");  // this tile's B+A done
        else        asm volatile("s_waitcnt vmcnt(0)" ::: "memory");
        // build P1 tile in LDS from regs: p = qm ? exp(S)*ri : 0
        {
            f16x8 v0 = (kt & 1) ? bB0 : bA0;
            f16x8 v1 = (kt & 1) ? bB1 : bA1;
            unsigned bits = (unsigned)(qbits >> (kt * 8)) & 0xffu;
            unsigned short p0[8], p1[8];
#pragma unroll
            for (int j = 0; j < 8; ++j)
                p0[j] = (bits >> j) & 1u ? bf16rne(__expf((float)v0[j]) * ri0) : (unsigned short)0;
#pragma unroll
            for (int j = 0; j < 8; ++j)
                p1[j] = (bits >> j) & 1u ? bf16rne(__expf((float)v1[j]) * ri1) : (unsigned short)0;
            *(us8*)&Bs[r0 * 64 + sl * 8] = *(const us8*)&p0[0];
            *(us8*)&Bs[r1 * 64 + sl * 8] = *(const us8*)&p1[0];
        }
        asm volatile("s_waitcnt lgkmcnt(0)" ::: "memory");
        __builtin_amdgcn_s_barrier();
        __builtin_amdgcn_sched_barrier(0);
        const short* Ac = As + cur * (256 * 64);
#pragma unroll
        for (int ks = 0; ks < 2; ++ks) {
            int kg = ks * 4 + (l >> 4);
            bf16x8 af[4], bfr[4];
#pragma unroll
            for (int ms = 0; ms < 4; ++ms) {
                int m = wn * 64 + ms * 16 + (l & 15);
                af[ms] = *(const bf16x8*)&Ac[m * 64 + (kg ^ (m & 7)) * 8];
            }
#pragma unroll
            for (int ns = 0; ns < 4; ++ns) {
                int cc = wc * 64 + ns * 16 + (l & 15);
                bfr[ns] = *(const bf16x8*)&Bs[cc * 64 + (kg ^ (cc & 7)) * 8];
            }
#pragma unroll
            for (int ms = 0; ms < 4; ++ms)
#pragma unroll
                for (int ns = 0; ns < 4; ++ns)
                    acc[ms][ns] = __builtin_amdgcn_mfma_f32_16x16x32_bf16(af[ms], bfr[ns], acc[ms][ns], 0, 0, 0);
        }
        __builtin_amdgcn_s_barrier();        // all waves done reading As[cur]+Bs
        __builtin_amdgcn_sched_barrier(0);
        if (kt < 6) {
            if (kt & 1) { LOAD_B(bB0, bB1, kt + 2); }
            else        { LOAD_B(bA0, bA1, kt + 2); }
            STAGE_A(cur, kt + 2);
        }
        cur ^= 1;
    }
#undef STAGE_A
#undef LOAD_B
#pragma unroll
    for (int ms = 0; ms < 4; ++ms) {
        int nb = wn * 64 + ms * 16 + (l >> 4) * 4;
#pragma unroll
        for (int ns = 0; ns < 4; ++ns) {
            int c = c0 + wc * 64 + ns * 16 + (l & 15);
#pragma unroll
            for (int r = 0; r < 4; ++r) {
                int n = nb + r;
                float a = acc[ms][ns][r];
                if (n < 128) {
                    float cv = C[((size_t)b * D_ + n) * LC + c];
                    out[((size_t)b * 512 + n) * LC + c] = cv;          // plane 0: Ct
                    out[((size_t)b * 512 + 128 + n) * LC + c] = a;     // plane 1: A
                    out[((size_t)b * 512 + 256 + n) * LC + c] = cv * a;// plane 2: Ct*A
                } else {
                    int dd = n - 128;
                    float cv = C[((size_t)b * D_ + dd) * LC + c];
                    out[((size_t)b * 512 + 384 + dd) * LC + c] = cv * a;// plane 3: Ct*Bm
                }
            }
        }
    }
}

extern "C" void kernel_launch(void* const* d_in, const int* in_sizes, int n_in,
                              void* d_out, int out_size, void* d_ws, size_t ws_size,
                              hipStream_t stream) {
    const float* C     = (const float*)d_in[0];
    const float* Q     = (const float*)d_in[1];
    const int*   Cmask = (const int*)d_in[2];
    const int*   Qmask = (const int*)d_in[3];
    const float* w_c   = (const float*)d_in[4];
    const float* w_q   = (const float*)d_in[5];
    const float* w_mul = (const float*)d_in[6];
    const float* bias  = (const float*)d_in[7];
    float* out = (float*)d_out;

    _Float16* S16 = (_Float16*)d_ws;                      // B*LC*LQ fp16  = 67.1 MB (stays RAW)
    short* Cb16 = (short*)(S16 + (size_t)B_ * LC * LQ);   // B*D*LC bf16   = 16.8 MB
    short* Ctw  = Cb16 + (size_t)B_ * D_ * LC;            // B*LC*D bf16   = 16.8 MB
    short* Qt16 = Ctw + (size_t)B_ * LC * D_;             // B*LQ*D bf16   =  4.2 MB
    short* Wf   = Qt16 + (size_t)B_ * LQ * D_;            // B*256*LQ bf16 =  8.4 MB
    float* s0     = (float*)(Wf + (size_t)B_ * 256 * LQ); // B*LC
    float* s1     = s0 + B_ * LC;                         // B*LQ
    float* colmax = s1 + B_ * LQ;                         // B*LQ
    float* colsum = colmax + B_ * LQ;                     // B*LQ
    float* rowsum = colsum + B_ * LQ;                     // B*LC
    float* pm     = rowsum + B_ * LC;                     // CCH*B*LQ = 1 MB
    float* pl     = pm + (size_t)CCH * B_ * LQ;           // CCH*B*LQ = 1 MB
    float* plr    = pl + (size_t)CCH * B_ * LQ;           // RCH*B*LC = 1 MB

    hipLaunchKernelGGL(k_dotw, dim3(B_ * LC / 256), dim3(256), 0, stream, C, w_c, s0, LC);
    hipLaunchKernelGGL(k_dotw, dim3(B_ * LQ / 256), dim3(256), 0, stream, Q, w_q, s1, LQ);
    hipLaunchKernelGGL(k_prep_C, dim3(LC / 64, B_), dim3(256), 0, stream, C, w_mul, Ctw, Cb16);
    hipLaunchKernelGGL(k_prep_Q, dim3(LQ / 64, B_), dim3(256), 0, stream, Q, Qt16, Wf);
    // k_S emits S16 + col partials (pm/pl) + row-sum partials (plr)
    hipLaunchKernelGGL(k_S_mfma, dim3((LC / 128) * (LQ / 128), B_), dim3(256), 0, stream,
                       Ctw, Qt16, s0, s1, bias, Cmask, Qmask, S16, pm, pl, plr);
    hipLaunchKernelGGL(k_comb, dim3((B_ * LQ + B_ * LC) / 256), dim3(256), 0, stream,
                       pm, pl, plr, colmax, colsum, rowsum);
    // V2 GEMM, 512-thread wave-group split (reads raw S; no P1 writeback)
    hipLaunchKernelGGL(k_V2_mfma, dim3(LQ / 64, B_), dim3(512), 0, stream,
                       Cb16, S16, Cmask, colmax, colsum, Wf);
    // OUT GEMM computes row-softmax on the fly from raw S16
    hipLaunchKernelGGL(k_out_mfma, dim3(LC / 128, B_), dim3(512), 0, stream,
                       S16, Wf, C, Qmask, rowsum, out);
}